// Round 1
// baseline (356.700 us; speedup 1.0000x reference)
//
#include <hip/hip_runtime.h>

#define IN_SIZE 4096
#define OUT_SIZE 8192

__device__ __forceinline__ float softplus_fast(float r) {
    // softplus(r) = max(r,0) + log1p(exp(-|r|)); fast-math variants are fine
    // for the 7.6e-2 absmax threshold.
    float a = __builtin_fabsf(r);
    return fmaxf(r, 0.0f) + __logf(1.0f + __expf(-a));
}

__global__ __launch_bounds__(256) void vlinear_matvec(
    const float* __restrict__ x,
    const float* __restrict__ mu,
    const float* __restrict__ rho,
    const float* __restrict__ bias_mu,
    const float* __restrict__ bias_rho,
    const float* __restrict__ eps_w,
    const float* __restrict__ eps_b,
    float* __restrict__ out)
{
    const int row = blockIdx.x;
    const int tid = threadIdx.x;
    const size_t base = (size_t)row * IN_SIZE;

    const float4* __restrict__ mu4  = (const float4*)(mu    + base);
    const float4* __restrict__ rho4 = (const float4*)(rho   + base);
    const float4* __restrict__ ew4  = (const float4*)(eps_w + base);
    const float4* __restrict__ x4   = (const float4*)x;

    float acc = 0.0f;
    // 4096 floats per row = 1024 float4s; 256 threads -> 4 iterations.
    #pragma unroll
    for (int k = 0; k < 4; ++k) {
        const int idx = k * 256 + tid;           // coalesced: lane i -> 16B chunk i
        const float4 m = mu4[idx];
        const float4 r = rho4[idx];
        const float4 e = ew4[idx];
        const float4 xv = x4[idx];
        acc += (m.x + softplus_fast(r.x) * e.x) * xv.x;
        acc += (m.y + softplus_fast(r.y) * e.y) * xv.y;
        acc += (m.z + softplus_fast(r.z) * e.z) * xv.z;
        acc += (m.w + softplus_fast(r.w) * e.w) * xv.w;
    }

    // Wave-64 reduction.
    #pragma unroll
    for (int off = 32; off > 0; off >>= 1)
        acc += __shfl_down(acc, off, 64);

    // Cross-wave (4 waves) reduction via LDS.
    __shared__ float s_partial[4];
    const int wave = tid >> 6;
    const int lane = tid & 63;
    if (lane == 0) s_partial[wave] = acc;
    __syncthreads();

    if (tid == 0) {
        float sum = s_partial[0] + s_partial[1] + s_partial[2] + s_partial[3];
        const float b = bias_mu[row] + softplus_fast(bias_rho[row]) * eps_b[row];
        out[row] = sum + b;
    }
}

extern "C" void kernel_launch(void* const* d_in, const int* in_sizes, int n_in,
                              void* d_out, int out_size, void* d_ws, size_t ws_size,
                              hipStream_t stream) {
    const float* x        = (const float*)d_in[0];
    const float* mu       = (const float*)d_in[1];
    const float* rho      = (const float*)d_in[2];
    const float* bias_mu  = (const float*)d_in[3];
    const float* bias_rho = (const float*)d_in[4];
    const float* eps_w    = (const float*)d_in[5];
    const float* eps_b    = (const float*)d_in[6];
    float* out = (float*)d_out;

    vlinear_matvec<<<OUT_SIZE, 256, 0, stream>>>(
        x, mu, rho, bias_mu, bias_rho, eps_w, eps_b, out);
}